// Round 4
// baseline (270.585 us; speedup 1.0000x reference)
//
#include <hip/hip_runtime.h>
#include <cstdint>
#include <cstddef>

#define EPSF 1e-6f

typedef __attribute__((ext_vector_type(4))) float f32x4;
typedef __attribute__((ext_vector_type(8))) short s16x8;
typedef union { s16x8 v; unsigned u[4]; } s16x8u;

static __device__ __forceinline__ unsigned short f2bf(float f) {
    unsigned u = __float_as_uint(f);
    u += 0x7FFFu + ((u >> 16) & 1u);
    return (unsigned short)(u >> 16);
}
static __device__ __forceinline__ float bf2f(unsigned short h) {
    return __uint_as_float(((unsigned)h) << 16);
}
// fp32 -> (bf16 hi, bf16 lo) packed in one u32; v ~= hi + lo to ~17 bits
static __device__ __forceinline__ unsigned packHL(float v) {
    unsigned short h = f2bf(v);
    float r = v - bf2f(h);
    unsigned short l = f2bf(r);
    return ((unsigned)h << 16) | (unsigned)l;
}

// ws layout (4B units):
//   [0    ..  575]  w1t branch0: [wv][chsub][cg][k] transposed normalized taps
//   [576  .. 1151]  w1t branch1
//   [1152 .. 9343]  w2 branch0, bf16 hi/lo packed u32 [128][64]
//   [9344 ..17535]  w2 branch1, bf16 hi/lo packed u32 [128][64]
//   [17536..17537]  (unused)
//   [17538..17601]  s1row[64]
//   [17602..17729]  s2row[128]

// grid 33 x 256: blocks 0..31 -> s2row (one wave per w2 row), block 32 -> s1row
__global__ __launch_bounds__(256) void prep_sums(const float* __restrict__ w1,
                                                 const float* __restrict__ w2,
                                                 float* __restrict__ ws) {
    const int bid = blockIdx.x;
    const int t = threadIdx.x;
    const int lane = t & 63;
    const int wv = t >> 6;
    if (bid < 32) {
        const int row = bid * 4 + wv;
        float v = w2[row * 64 + lane];
        float s = v * v;
        #pragma unroll
        for (int d = 32; d > 0; d >>= 1) s += __shfl_down(s, d);
        if (lane == 0) ws[17602 + row] = s;
    } else if (t < 64) {
        float rs = 0.f;
        #pragma unroll
        for (int k = 0; k < 9; ++k) { float v = w1[t * 9 + k]; rs += v * v; }
        ws[17538 + t] = rs;
    }
}

// grid 35 x 256: each wave redundantly reduces tot1/tot2 from row sums (no
// atomics, no LDS), then packs normalized weights.
__global__ __launch_bounds__(256) void prep_pack(const float* __restrict__ w1,
                                                 const float* __restrict__ w2,
                                                 float* __restrict__ ws) {
    const int t = threadIdx.x;
    const int lane = t & 63;
    const int gid = blockIdx.x * 256 + t;

    float a = ws[17538 + lane];
    float b0 = ws[17602 + lane] + ws[17602 + 64 + lane];
    #pragma unroll
    for (int d = 32; d > 0; d >>= 1) {
        a += __shfl_xor(a, d);
        b0 += __shfl_xor(b0, d);
    }
    const float t1 = a, t2 = b0;

    unsigned* wsu = (unsigned*)ws;
    if (gid < 8192) {
        float v = w2[gid];
        float q = v * v;
        wsu[1152 + gid] = packHL(q / t2);
        wsu[9344 + gid] = packHL(q / ws[17602 + (gid >> 6)]);
    } else if (gid < 8768) {
        const int i = gid - 8192;
        const int c = i / 9;
        const int k = i - c * 9;
        const int idx = (c >> 4) * 144 + (c & 3) * 36 + ((c >> 2) & 3) * 9 + k;
        float v = w1[i];
        float q = v * v;
        ws[idx] = q / t1;
        ws[576 + idx] = q / ws[17538 + c];
    }
}

// grid: (32, 2, 31)  block: 256.  b = blockIdx.x (fastest -> XCD spread over
// batches, h-sequential per XCD for L2 row reuse), hg = blockIdx.z, 2 output
// rows h0=2*hg, h0+1 from 4 input rows.
// phase 1: lane = (chsub = lane>>4, c4 = lane&15). float4 loads of 4 rows,
//          2 shfls/row, 72 taps -> 8 px results, packed bf16 hi/lo into
//          rotT[pxl][c] (stride 65, pxl = row*64 + px).
// phase 2: wave wv -> out-channels [wv*32,wv*32+32) x 128 pxl via
//          mfma_f32_16x16x32_bf16, 3-term hi/lo split (AhBh+AhBl+AlBh).
__global__ __launch_bounds__(256, 4) void conv_fused(const float* __restrict__ x,
                                                     const float* __restrict__ ws,
                                                     float* __restrict__ out) {
    const int b = blockIdx.x;
    const int branch = blockIdx.y;
    const int hg = blockIdx.z;
    const int h0 = hg * 2;
    const int t = threadIdx.x;
    const int lane = t & 63;
    const int wv = __builtin_amdgcn_readfirstlane(t >> 6);
    const int lm = lane & 15;
    const int quad = lane >> 4;
    const int c4 = lm;
    const int chsub = quad;

    __shared__ unsigned rotT[128 * 65];  // [pxl][c], stride 65 dwords

    const float* __restrict__ w1t = ws + branch * 576;
    const unsigned* __restrict__ w2p = (const unsigned*)ws + 1152 + branch * 8192;
    const float* __restrict__ xb = x + (size_t)(b * 2 + branch) * (64 * 4096);

    // ---- phase 1: depthwise 3x3, 2 output rows, float4-vectorized ----
    const float* xrow = xb + h0 * 64 + 4 * c4;
    #pragma unroll 2
    for (int cg = 0; cg < 4; ++cg) {
        const int c = wv * 16 + cg * 4 + chsub;
        const float* xp = xrow + c * 4096;
        float4 v0 = *(const float4*)xp;
        float4 v1 = *(const float4*)(xp + 64);
        float4 v2 = *(const float4*)(xp + 128);
        float4 v3 = *(const float4*)(xp + 192);
        if (branch) {
            v0.x = __logf(v0.x + EPSF); v0.y = __logf(v0.y + EPSF);
            v0.z = __logf(v0.z + EPSF); v0.w = __logf(v0.w + EPSF);
            v1.x = __logf(v1.x + EPSF); v1.y = __logf(v1.y + EPSF);
            v1.z = __logf(v1.z + EPSF); v1.w = __logf(v1.w + EPSF);
            v2.x = __logf(v2.x + EPSF); v2.y = __logf(v2.y + EPSF);
            v2.z = __logf(v2.z + EPSF); v2.w = __logf(v2.w + EPSF);
            v3.x = __logf(v3.x + EPSF); v3.y = __logf(v3.y + EPSF);
            v3.z = __logf(v3.z + EPSF); v3.w = __logf(v3.w + EPSF);
        }
        const float sx0 = __shfl_down(v0.x, 1), sy0 = __shfl_down(v0.y, 1);
        const float sx1 = __shfl_down(v1.x, 1), sy1 = __shfl_down(v1.y, 1);
        const float sx2 = __shfl_down(v2.x, 1), sy2 = __shfl_down(v2.y, 1);
        const float sx3 = __shfl_down(v3.x, 1), sy3 = __shfl_down(v3.y, 1);
        const float* wc = w1t + wv * 144 + chsub * 36 + cg * 9;  // L1-hot
        const float w0 = wc[0], w1_ = wc[1], w2_ = wc[2];
        const float w3 = wc[3], w4 = wc[4], w5 = wc[5];
        const float w6 = wc[6], w7 = wc[7], w8 = wc[8];
        // out row 0 (input rows v0,v1,v2); px = 4*c4 + i; px 62/63 discarded
        float p0 = v0.x * w0 + v0.y * w1_ + v0.z * w2_
                 + v1.x * w3 + v1.y * w4  + v1.z * w5
                 + v2.x * w6 + v2.y * w7  + v2.z * w8;
        float p1 = v0.y * w0 + v0.z * w1_ + v0.w * w2_
                 + v1.y * w3 + v1.z * w4  + v1.w * w5
                 + v2.y * w6 + v2.z * w7  + v2.w * w8;
        float p2 = v0.z * w0 + v0.w * w1_ + sx0 * w2_
                 + v1.z * w3 + v1.w * w4  + sx1 * w5
                 + v2.z * w6 + v2.w * w7  + sx2 * w8;
        float p3 = v0.w * w0 + sx0 * w1_ + sy0 * w2_
                 + v1.w * w3 + sx1 * w4  + sy1 * w5
                 + v2.w * w6 + sx2 * w7  + sy2 * w8;
        // out row 1 (input rows v1,v2,v3)
        float q0 = v1.x * w0 + v1.y * w1_ + v1.z * w2_
                 + v2.x * w3 + v2.y * w4  + v2.z * w5
                 + v3.x * w6 + v3.y * w7  + v3.z * w8;
        float q1 = v1.y * w0 + v1.z * w1_ + v1.w * w2_
                 + v2.y * w3 + v2.z * w4  + v2.w * w5
                 + v3.y * w6 + v3.z * w7  + v3.w * w8;
        float q2 = v1.z * w0 + v1.w * w1_ + sx1 * w2_
                 + v2.z * w3 + v2.w * w4  + sx2 * w5
                 + v3.z * w6 + v3.w * w7  + sx3 * w8;
        float q3 = v1.w * w0 + sx1 * w1_ + sy1 * w2_
                 + v2.w * w3 + sx2 * w4  + sy2 * w5
                 + v3.w * w6 + sx3 * w7  + sy3 * w8;
        unsigned* rp = &rotT[(4 * c4) * 65 + c];
        rp[0]   = packHL(p0);
        rp[65]  = packHL(p1);
        rp[130] = packHL(p2);
        rp[195] = packHL(p3);
        unsigned* rq = rp + 64 * 65;
        rq[0]   = packHL(q0);
        rq[65]  = packHL(q1);
        rq[130] = packHL(q2);
        rq[195] = packHL(q3);
    }

    // ---- A-fragment raw loads (L2-hot) — latency hides under barrier wait ----
    unsigned araw[2][2][8];
    #pragma unroll
    for (int mt = 0; mt < 2; ++mt) {
        #pragma unroll
        for (int kk = 0; kk < 2; ++kk) {
            const unsigned* p = w2p + (wv * 32 + mt * 16 + lm) * 64 + kk * 32 + quad * 8;
            #pragma unroll
            for (int j = 0; j < 8; ++j) araw[mt][kk][j] = p[j];
        }
    }
    __syncthreads();

    // unpack A into bf16 hi/lo fragments via v_perm
    s16x8u aH[2][2], aL[2][2];
    #pragma unroll
    for (int mt = 0; mt < 2; ++mt)
        #pragma unroll
        for (int kk = 0; kk < 2; ++kk)
            #pragma unroll
            for (int j2 = 0; j2 < 4; ++j2) {
                unsigned u0 = araw[mt][kk][2 * j2], u1 = araw[mt][kk][2 * j2 + 1];
                aH[mt][kk].u[j2] = __builtin_amdgcn_perm(u1, u0, 0x07060302u);
                aL[mt][kk].u[j2] = __builtin_amdgcn_perm(u1, u0, 0x05040100u);
            }

    f32x4 acc[2][8];
    #pragma unroll
    for (int mt = 0; mt < 2; ++mt)
        #pragma unroll
        for (int nt = 0; nt < 8; ++nt)
            acc[mt][nt] = (f32x4){0.f, 0.f, 0.f, 0.f};

    #pragma unroll
    for (int nt = 0; nt < 8; ++nt) {
        #pragma unroll
        for (int kk = 0; kk < 2; ++kk) {
            // B fragment: B[k=quad*8+j][n=lane&15] = rotT[pxl][c]
            const unsigned* lp = &rotT[(nt * 16 + lm) * 65 + kk * 32 + quad * 8];
            s16x8u bH, bL;
            #pragma unroll
            for (int j2 = 0; j2 < 4; ++j2) {
                unsigned u0 = lp[2 * j2], u1 = lp[2 * j2 + 1];
                bH.u[j2] = __builtin_amdgcn_perm(u1, u0, 0x07060302u);
                bL.u[j2] = __builtin_amdgcn_perm(u1, u0, 0x05040100u);
            }
            #pragma unroll
            for (int mt = 0; mt < 2; ++mt) {
                acc[mt][nt] = __builtin_amdgcn_mfma_f32_16x16x32_bf16(aH[mt][kk].v, bH.v, acc[mt][nt], 0, 0, 0);
                acc[mt][nt] = __builtin_amdgcn_mfma_f32_16x16x32_bf16(aH[mt][kk].v, bL.v, acc[mt][nt], 0, 0, 0);
                acc[mt][nt] = __builtin_amdgcn_mfma_f32_16x16x32_bf16(aL[mt][kk].v, bH.v, acc[mt][nt], 0, 0, 0);
            }
        }
    }

    // ---- epilogue: D row = oc (quad*4+reg), col = pxl (nt*16 + lane&15) ----
    #pragma unroll
    for (int mt = 0; mt < 2; ++mt) {
        const int oc0 = wv * 32 + mt * 16 + quad * 4;
        #pragma unroll
        for (int nt = 0; nt < 8; ++nt) {
            const int pxl = nt * 16 + lm;
            const int row = pxl >> 6;
            const int col = pxl & 63;
            if (col < 62) {
                const size_t base =
                    ((size_t)((b * 2 + branch) * 128 + oc0)) * 3844 +
                    (size_t)(h0 + row) * 62 + col;
                #pragma unroll
                for (int r = 0; r < 4; ++r) {
                    float v = acc[mt][nt][r];
                    if (branch) v = __expf(v);
                    __builtin_nontemporal_store(v, &out[base + (size_t)r * 3844]);
                }
            }
        }
    }
}

extern "C" void kernel_launch(void* const* d_in, const int* in_sizes, int n_in,
                              void* d_out, int out_size, void* d_ws, size_t ws_size,
                              hipStream_t stream) {
    const float* x  = (const float*)d_in[0];
    const float* w1 = (const float*)d_in[1];
    const float* w2 = (const float*)d_in[2];
    float* out = (float*)d_out;
    float* ws  = (float*)d_ws;

    prep_sums<<<33, 256, 0, stream>>>(w1, w2, ws);
    prep_pack<<<35, 256, 0, stream>>>(w1, w2, ws);

    dim3 grid(32, 2, 31);
    conv_fused<<<grid, 256, 0, stream>>>(x, ws, out);
}

// Round 5
// 201.042 us; speedup vs baseline: 1.3459x; 1.3459x over previous
//
#include <hip/hip_runtime.h>
#include <cstdint>
#include <cstddef>

#define EPSF 1e-6f

typedef __attribute__((ext_vector_type(4))) float f32x4;
typedef __attribute__((ext_vector_type(8))) short s16x8;
typedef union { s16x8 v; unsigned u[4]; } s16x8u;

static __device__ __forceinline__ unsigned short f2bf(float f) {
    unsigned u = __float_as_uint(f);
    u += 0x7FFFu + ((u >> 16) & 1u);
    return (unsigned short)(u >> 16);
}
static __device__ __forceinline__ float bf2f(unsigned short h) {
    return __uint_as_float(((unsigned)h) << 16);
}
// two floats -> (H = bf16(b)<<16 | bf16(a), L = residual pair), a+resid ~17 bits
static __device__ __forceinline__ void pack2(float a, float b, unsigned& H, unsigned& L) {
    unsigned short ha = f2bf(a), hb = f2bf(b);
    unsigned short la = f2bf(a - bf2f(ha)), lb = f2bf(b - bf2f(hb));
    H = ((unsigned)hb << 16) | (unsigned)ha;
    L = ((unsigned)lb << 16) | (unsigned)la;
}

// ws layout (4B units):
//   [0    ..  575]  w1n branch0: [c][9] normalized taps (fp32)
//   [576  .. 1151]  w1n branch1
//   [1152 .. 5247]  w2H branch0 [128][32] u32 c-pair hi
//   [5248 .. 9343]  w2L branch0 [128][32] u32 c-pair lo
//   [9344 ..13439]  w2H branch1
//   [13440..17535]  w2L branch1
//   [17538..17601]  s1row[64]
//   [17602..17729]  s2row[128]

// grid 33 x 256: blocks 0..31 -> s2row (one wave per w2 row), block 32 -> s1row
__global__ __launch_bounds__(256) void prep_sums(const float* __restrict__ w1,
                                                 const float* __restrict__ w2,
                                                 float* __restrict__ ws) {
    const int bid = blockIdx.x;
    const int t = threadIdx.x;
    const int lane = t & 63;
    const int wv = t >> 6;
    if (bid < 32) {
        const int row = bid * 4 + wv;
        float v = w2[row * 64 + lane];
        float s = v * v;
        #pragma unroll
        for (int d = 32; d > 0; d >>= 1) s += __shfl_down(s, d);
        if (lane == 0) ws[17602 + row] = s;
    } else if (t < 64) {
        float rs = 0.f;
        #pragma unroll
        for (int k = 0; k < 9; ++k) { float v = w1[t * 9 + k]; rs += v * v; }
        ws[17538 + t] = rs;
    }
}

// grid 19 x 256: each wave redundantly reduces tot1/tot2 (no atomics), then
// packs normalized weights. gid<4096: one c-PAIR of one w2 row, both branches.
__global__ __launch_bounds__(256) void prep_pack(const float* __restrict__ w1,
                                                 const float* __restrict__ w2,
                                                 float* __restrict__ ws) {
    const int t = threadIdx.x;
    const int lane = t & 63;
    const int gid = blockIdx.x * 256 + t;

    float a = ws[17538 + lane];
    float b0 = ws[17602 + lane] + ws[17602 + 64 + lane];
    #pragma unroll
    for (int d = 32; d > 0; d >>= 1) {
        a += __shfl_xor(a, d);
        b0 += __shfl_xor(b0, d);
    }
    const float t1 = a, t2 = b0;

    unsigned* wsu = (unsigned*)ws;
    if (gid < 4096) {
        const int row = gid >> 5;
        const int cp = gid & 31;
        float v0 = w2[row * 64 + 2 * cp];
        float v1 = w2[row * 64 + 2 * cp + 1];
        float q0 = v0 * v0, q1 = v1 * v1;
        const float rs = ws[17602 + row];
        unsigned H, L;
        pack2(q0 / t2, q1 / t2, H, L);
        wsu[1152 + row * 32 + cp] = H;
        wsu[5248 + row * 32 + cp] = L;
        pack2(q0 / rs, q1 / rs, H, L);
        wsu[9344 + row * 32 + cp] = H;
        wsu[13440 + row * 32 + cp] = L;
    } else if (gid < 4672) {
        const int i = gid - 4096;
        const int c = i / 9;
        const int k = i - c * 9;
        float v = w1[i];
        float q = v * v;
        ws[c * 9 + k] = q / t1;
        ws[576 + c * 9 + k] = q / ws[17538 + c];
    }
}

// grid: (32, 2, 31)  block: 512 (8 waves).
// Block computes 2 output rows (h0=2*hg, h0+1) for one (b, branch).
// phase 1: (wave w, quad q) owns channel-pair cpair=w*4+q (channels 2cpair,
//          2cpair+1); lane lm = 4-px column group. float4 loads of 4 input
//          rows x 2 channels, 2 shfls/row/ch, 144 taps -> 16 results ->
//          pack2 -> rotH/rotL[pxl][cpair] (stride 33 u32, 2-way banks).
// phase 2: wave w -> oc tile (w&3)*32..+32, output row half=w>>2.
//          B-frag = 1 ds_read_b128 from rotH + 1 from rotL (zero unpack);
//          A-frag = raw dwordx4 from pre-packed w2H/w2L.
//          3-term hi/lo split: AhBh + AhBl + AlBh.
__global__ __launch_bounds__(512) void conv_fused(const float* __restrict__ x,
                                                  const float* __restrict__ ws,
                                                  float* __restrict__ out) {
    const int b = blockIdx.x;
    const int branch = blockIdx.y;
    const int hg = blockIdx.z;
    const int h0 = hg * 2;
    const int t = threadIdx.x;
    const int lane = t & 63;
    const int w = __builtin_amdgcn_readfirstlane(t >> 6);
    const int lm = lane & 15;
    const int q = lane >> 4;

    __shared__ unsigned rotH[128 * 33];
    __shared__ unsigned rotL[128 * 33];

    const float* __restrict__ w1n = ws + branch * 576;
    const unsigned* __restrict__ wsu = (const unsigned*)ws;
    const unsigned* __restrict__ w2H = wsu + 1152 + branch * 8192;
    const unsigned* __restrict__ w2L = w2H + 4096;
    const float* __restrict__ xb = x + (size_t)(b * 2 + branch) * (64 * 4096);

    // ---- phase 1: depthwise 3x3 on 2 channels, 2 output rows ----
    {
        const int cpair = w * 4 + q;
        const int c0 = 2 * cpair;
        const float* xp0 = xb + c0 * 4096 + h0 * 64 + 4 * lm;
        const float* xp1 = xp0 + 4096;
        float4 va[4], vb[4];
        #pragma unroll
        for (int r = 0; r < 4; ++r) va[r] = *(const float4*)(xp0 + r * 64);
        #pragma unroll
        for (int r = 0; r < 4; ++r) vb[r] = *(const float4*)(xp1 + r * 64);
        if (branch) {
            #pragma unroll
            for (int r = 0; r < 4; ++r) {
                va[r].x = __logf(va[r].x + EPSF); va[r].y = __logf(va[r].y + EPSF);
                va[r].z = __logf(va[r].z + EPSF); va[r].w = __logf(va[r].w + EPSF);
                vb[r].x = __logf(vb[r].x + EPSF); vb[r].y = __logf(vb[r].y + EPSF);
                vb[r].z = __logf(vb[r].z + EPSF); vb[r].w = __logf(vb[r].w + EPSF);
            }
        }
        float sax[4], say[4], sbx[4], sby[4];
        #pragma unroll
        for (int r = 0; r < 4; ++r) {
            sax[r] = __shfl_down(va[r].x, 1); say[r] = __shfl_down(va[r].y, 1);
            sbx[r] = __shfl_down(vb[r].x, 1); sby[r] = __shfl_down(vb[r].y, 1);
        }
        const float* wc0 = w1n + c0 * 9;
        const float* wc1 = wc0 + 9;
        float pa[2][4], pb[2][4];
        #pragma unroll
        for (int row = 0; row < 2; ++row) {
            // output row `row` uses input rows row, row+1, row+2
            #pragma unroll
            for (int rr = 0; rr < 3; ++rr) {
                const float4 u = va[row + rr];
                const float ux1 = sax[row + rr], uy1 = say[row + rr];
                const float t0 = wc0[rr * 3], t1_ = wc0[rr * 3 + 1], t2_ = wc0[rr * 3 + 2];
                if (rr == 0) {
                    pa[row][0] = u.x * t0 + u.y * t1_ + u.z * t2_;
                    pa[row][1] = u.y * t0 + u.z * t1_ + u.w * t2_;
                    pa[row][2] = u.z * t0 + u.w * t1_ + ux1 * t2_;
                    pa[row][3] = u.w * t0 + ux1 * t1_ + uy1 * t2_;
                } else {
                    pa[row][0] += u.x * t0 + u.y * t1_ + u.z * t2_;
                    pa[row][1] += u.y * t0 + u.z * t1_ + u.w * t2_;
                    pa[row][2] += u.z * t0 + u.w * t1_ + ux1 * t2_;
                    pa[row][3] += u.w * t0 + ux1 * t1_ + uy1 * t2_;
                }
            }
            #pragma unroll
            for (int rr = 0; rr < 3; ++rr) {
                const float4 u = vb[row + rr];
                const float ux1 = sbx[row + rr], uy1 = sby[row + rr];
                const float t0 = wc1[rr * 3], t1_ = wc1[rr * 3 + 1], t2_ = wc1[rr * 3 + 2];
                if (rr == 0) {
                    pb[row][0] = u.x * t0 + u.y * t1_ + u.z * t2_;
                    pb[row][1] = u.y * t0 + u.z * t1_ + u.w * t2_;
                    pb[row][2] = u.z * t0 + u.w * t1_ + ux1 * t2_;
                    pb[row][3] = u.w * t0 + ux1 * t1_ + uy1 * t2_;
                } else {
                    pb[row][0] += u.x * t0 + u.y * t1_ + u.z * t2_;
                    pb[row][1] += u.y * t0 + u.z * t1_ + u.w * t2_;
                    pb[row][2] += u.z * t0 + u.w * t1_ + ux1 * t2_;
                    pb[row][3] += u.w * t0 + ux1 * t1_ + uy1 * t2_;
                }
            }
        }
        #pragma unroll
        for (int row = 0; row < 2; ++row) {
            #pragma unroll
            for (int i = 0; i < 4; ++i) {
                const int pxl = row * 64 + 4 * lm + i;
                unsigned H, L;
                pack2(pa[row][i], pb[row][i], H, L);
                rotH[pxl * 33 + cpair] = H;
                rotL[pxl * 33 + cpair] = L;
            }
        }
    }

    // ---- A-fragment loads (L2-hot, pre-packed) — latency hides under barrier ----
    const int woc = (w & 3) * 32;
    const int half = w >> 2;
    s16x8u aH[2][2], aL[2][2];
    #pragma unroll
    for (int mt = 0; mt < 2; ++mt) {
        #pragma unroll
        for (int kk = 0; kk < 2; ++kk) {
            const int off = (woc + mt * 16 + lm) * 32 + kk * 16 + q * 4;
            const unsigned* ph = w2H + off;
            const unsigned* pl = w2L + off;
            #pragma unroll
            for (int j = 0; j < 4; ++j) {
                aH[mt][kk].u[j] = ph[j];
                aL[mt][kk].u[j] = pl[j];
            }
        }
    }
    __syncthreads();

    // ---- phase 2: MFMA GEMM, wave tile = 32 oc x 64 px (one output row) ----
    f32x4 acc[2][4];
    #pragma unroll
    for (int mt = 0; mt < 2; ++mt)
        #pragma unroll
        for (int nt = 0; nt < 4; ++nt)
            acc[mt][nt] = (f32x4){0.f, 0.f, 0.f, 0.f};

    #pragma unroll
    for (int nt = 0; nt < 4; ++nt) {
        #pragma unroll
        for (int kk = 0; kk < 2; ++kk) {
            const int idx = (half * 64 + nt * 16 + lm) * 33 + kk * 16 + q * 4;
            s16x8u bH, bL;
            #pragma unroll
            for (int j = 0; j < 4; ++j) bH.u[j] = rotH[idx + j];
            #pragma unroll
            for (int j = 0; j < 4; ++j) bL.u[j] = rotL[idx + j];
            #pragma unroll
            for (int mt = 0; mt < 2; ++mt) {
                acc[mt][nt] = __builtin_amdgcn_mfma_f32_16x16x32_bf16(aH[mt][kk].v, bH.v, acc[mt][nt], 0, 0, 0);
                acc[mt][nt] = __builtin_amdgcn_mfma_f32_16x16x32_bf16(aH[mt][kk].v, bL.v, acc[mt][nt], 0, 0, 0);
                acc[mt][nt] = __builtin_amdgcn_mfma_f32_16x16x32_bf16(aL[mt][kk].v, bH.v, acc[mt][nt], 0, 0, 0);
            }
        }
    }

    // ---- epilogue: D row = oc (q*4+reg), col = nt*16+lm, out row h0+half ----
    #pragma unroll
    for (int mt = 0; mt < 2; ++mt) {
        const int oc0 = woc + mt * 16 + q * 4;
        #pragma unroll
        for (int nt = 0; nt < 4; ++nt) {
            const int col = nt * 16 + lm;
            if (col < 62) {
                const size_t base =
                    ((size_t)((b * 2 + branch) * 128 + oc0)) * 3844 +
                    (size_t)(h0 + half) * 62 + col;
                #pragma unroll
                for (int r = 0; r < 4; ++r) {
                    float v = acc[mt][nt][r];
                    if (branch) v = __expf(v);
                    out[base + (size_t)r * 3844] = v;
                }
            }
        }
    }
}

extern "C" void kernel_launch(void* const* d_in, const int* in_sizes, int n_in,
                              void* d_out, int out_size, void* d_ws, size_t ws_size,
                              hipStream_t stream) {
    const float* x  = (const float*)d_in[0];
    const float* w1 = (const float*)d_in[1];
    const float* w2 = (const float*)d_in[2];
    float* out = (float*)d_out;
    float* ws  = (float*)d_ws;

    prep_sums<<<33, 256, 0, stream>>>(w1, w2, ws);
    prep_pack<<<19, 256, 0, stream>>>(w1, w2, ws);

    dim3 grid(32, 2, 31);
    conv_fused<<<grid, 512, 0, stream>>>(x, ws, out);
}